// Round 4
// baseline (364.915 us; speedup 1.0000x reference)
//
#include <hip/hip_runtime.h>
#include <hip/hip_bf16.h>

// GRU-D cell: B=16384, I=128, D=16.
// K=2 batch rows per thread: each LDS float4 broadcast of U feeds 8 FMAs
// (2 rows x 4 outputs), halving per-element LDS-pipe cost (the R3 bottleneck:
// LDS broadcasts were ~123 us of per-CU LDS throughput).
// U/W/V/b for this block's feature i staged in LDS once (3.6 KB), read as
// same-address float4 broadcasts (conflict-free).
// Phased liveness keeps peak live floats ~96; __launch_bounds__(256,4)
// caps VGPR at 128 so nothing spills.

constexpr int I_TOT = 128;
constexpr int D_DIM = 16;

__device__ __forceinline__ float fast_sigmoid(float x) {
    float e = __expf(-x);
    return __builtin_amdgcn_rcpf(1.0f + e);
}

__device__ __forceinline__ float fast_tanh(float x) {
    x = fminf(fmaxf(x, -10.0f), 10.0f);
    float e = __expf(-2.0f * x);
    return (1.0f - e) * __builtin_amdgcn_rcpf(1.0f + e);
}

__global__ __launch_bounds__(256, 4) void gru_d_cell(
    const float* __restrict__ h,
    const float* __restrict__ X,
    const float* __restrict__ M,
    const float* __restrict__ gamma_h,
    const float* __restrict__ W_r,
    const float* __restrict__ W_z,
    const float* __restrict__ W_h,
    const float* __restrict__ U_r,
    const float* __restrict__ U_z,
    const float* __restrict__ U_h,
    const float* __restrict__ V_r,
    const float* __restrict__ V_z,
    const float* __restrict__ V_h,
    const float* __restrict__ b_r,
    const float* __restrict__ b_z,
    const float* __restrict__ b_h,
    float* __restrict__ out)
{
    __shared__ float sUr[256];
    __shared__ float sUz[256];
    __shared__ float sUh[256];
    __shared__ float sWr[16], sWz[16], sWh[16];
    __shared__ float sVr[16], sVz[16], sVh[16];
    __shared__ float sbr[16], sbz[16], sbh[16];

    const int i = blockIdx.y;        // block-uniform feature index
    const int t = threadIdx.x;

    sUr[t] = U_r[i * 256 + t];
    sUz[t] = U_z[i * 256 + t];
    sUh[t] = U_h[i * 256 + t];
    if (t < 16) {
        sWr[t] = W_r[i * 16 + t];
        sWz[t] = W_z[i * 16 + t];
        sWh[t] = W_h[i * 16 + t];
        sVr[t] = V_r[i * 16 + t];
        sVz[t] = V_z[i * 16 + t];
        sVh[t] = V_h[i * 16 + t];
        sbr[t] = b_r[i * 16 + t];
        sbz[t] = b_z[i * 16 + t];
        sbh[t] = b_h[i * 16 + t];
    }
    __syncthreads();

    // Two batch rows per thread, both coalesced across the block.
    const int b0 = blockIdx.x * 512 + t;        // rows [blk*512, blk*512+255]
    const int b1 = b0 + 256;                    // rows [blk*512+256, +511]
    const size_t base0 = ((size_t)b0 * I_TOT + i) * D_DIM;
    const size_t base1 = ((size_t)b1 * I_TOT + i) * D_DIM;

    // hh = h * gamma_h for both rows
    float hh0[D_DIM], hh1[D_DIM];
    #pragma unroll
    for (int k = 0; k < 4; ++k) {
        float4 hv = *reinterpret_cast<const float4*>(h + base0 + 4 * k);
        float4 gv = *reinterpret_cast<const float4*>(gamma_h + base0 + 4 * k);
        hh0[4 * k + 0] = hv.x * gv.x;
        hh0[4 * k + 1] = hv.y * gv.y;
        hh0[4 * k + 2] = hv.z * gv.z;
        hh0[4 * k + 3] = hv.w * gv.w;
    }
    #pragma unroll
    for (int k = 0; k < 4; ++k) {
        float4 hv = *reinterpret_cast<const float4*>(h + base1 + 4 * k);
        float4 gv = *reinterpret_cast<const float4*>(gamma_h + base1 + 4 * k);
        hh1[4 * k + 0] = hv.x * gv.x;
        hh1[4 * k + 1] = hv.y * gv.y;
        hh1[4 * k + 2] = hv.z * gv.z;
        hh1[4 * k + 3] = hv.w * gv.w;
    }

    const float xb0 = X[(size_t)b0 * I_TOT + i];
    const float mb0 = M[(size_t)b0 * I_TOT + i];
    const float xb1 = X[(size_t)b1 * I_TOT + i];
    const float mb1 = M[(size_t)b1 * I_TOT + i];

    // ---- Phase 1: accr = x*Wr + m*Vr + br + hh @ Ur ----
    float accr0[D_DIM], accr1[D_DIM];
    #pragma unroll
    for (int k = 0; k < 4; ++k) {
        float4 w = *reinterpret_cast<const float4*>(&sWr[4 * k]);
        float4 v = *reinterpret_cast<const float4*>(&sVr[4 * k]);
        float4 bi = *reinterpret_cast<const float4*>(&sbr[4 * k]);
        accr0[4 * k + 0] = fmaf(xb0, w.x, fmaf(mb0, v.x, bi.x));
        accr0[4 * k + 1] = fmaf(xb0, w.y, fmaf(mb0, v.y, bi.y));
        accr0[4 * k + 2] = fmaf(xb0, w.z, fmaf(mb0, v.z, bi.z));
        accr0[4 * k + 3] = fmaf(xb0, w.w, fmaf(mb0, v.w, bi.w));
        accr1[4 * k + 0] = fmaf(xb1, w.x, fmaf(mb1, v.x, bi.x));
        accr1[4 * k + 1] = fmaf(xb1, w.y, fmaf(mb1, v.y, bi.y));
        accr1[4 * k + 2] = fmaf(xb1, w.z, fmaf(mb1, v.z, bi.z));
        accr1[4 * k + 3] = fmaf(xb1, w.w, fmaf(mb1, v.w, bi.w));
    }
    #pragma unroll
    for (int d = 0; d < D_DIM; ++d) {
        const float hd0 = hh0[d];
        const float hd1 = hh1[d];
        #pragma unroll
        for (int k = 0; k < 4; ++k) {
            float4 u = *reinterpret_cast<const float4*>(&sUr[d * D_DIM + 4 * k]);
            accr0[4 * k + 0] = fmaf(hd0, u.x, accr0[4 * k + 0]);
            accr0[4 * k + 1] = fmaf(hd0, u.y, accr0[4 * k + 1]);
            accr0[4 * k + 2] = fmaf(hd0, u.z, accr0[4 * k + 2]);
            accr0[4 * k + 3] = fmaf(hd0, u.w, accr0[4 * k + 3]);
            accr1[4 * k + 0] = fmaf(hd1, u.x, accr1[4 * k + 0]);
            accr1[4 * k + 1] = fmaf(hd1, u.y, accr1[4 * k + 1]);
            accr1[4 * k + 2] = fmaf(hd1, u.z, accr1[4 * k + 2]);
            accr1[4 * k + 3] = fmaf(hd1, u.w, accr1[4 * k + 3]);
        }
    }

    // rhh = sigmoid(accr) * hh    (accr dies)
    float rhh0[D_DIM], rhh1[D_DIM];
    #pragma unroll
    for (int e = 0; e < D_DIM; ++e) {
        rhh0[e] = fast_sigmoid(accr0[e]) * hh0[e];
        rhh1[e] = fast_sigmoid(accr1[e]) * hh1[e];
    }

    // ---- Phase 2: acch = x*Wh + m*Vh + bh + rhh @ Uh ----
    float acch0[D_DIM], acch1[D_DIM];
    #pragma unroll
    for (int k = 0; k < 4; ++k) {
        float4 w = *reinterpret_cast<const float4*>(&sWh[4 * k]);
        float4 v = *reinterpret_cast<const float4*>(&sVh[4 * k]);
        float4 bi = *reinterpret_cast<const float4*>(&sbh[4 * k]);
        acch0[4 * k + 0] = fmaf(xb0, w.x, fmaf(mb0, v.x, bi.x));
        acch0[4 * k + 1] = fmaf(xb0, w.y, fmaf(mb0, v.y, bi.y));
        acch0[4 * k + 2] = fmaf(xb0, w.z, fmaf(mb0, v.z, bi.z));
        acch0[4 * k + 3] = fmaf(xb0, w.w, fmaf(mb0, v.w, bi.w));
        acch1[4 * k + 0] = fmaf(xb1, w.x, fmaf(mb1, v.x, bi.x));
        acch1[4 * k + 1] = fmaf(xb1, w.y, fmaf(mb1, v.y, bi.y));
        acch1[4 * k + 2] = fmaf(xb1, w.z, fmaf(mb1, v.z, bi.z));
        acch1[4 * k + 3] = fmaf(xb1, w.w, fmaf(mb1, v.w, bi.w));
    }
    #pragma unroll
    for (int d = 0; d < D_DIM; ++d) {
        const float rd0 = rhh0[d];
        const float rd1 = rhh1[d];
        #pragma unroll
        for (int k = 0; k < 4; ++k) {
            float4 u = *reinterpret_cast<const float4*>(&sUh[d * D_DIM + 4 * k]);
            acch0[4 * k + 0] = fmaf(rd0, u.x, acch0[4 * k + 0]);
            acch0[4 * k + 1] = fmaf(rd0, u.y, acch0[4 * k + 1]);
            acch0[4 * k + 2] = fmaf(rd0, u.z, acch0[4 * k + 2]);
            acch0[4 * k + 3] = fmaf(rd0, u.w, acch0[4 * k + 3]);
            acch1[4 * k + 0] = fmaf(rd1, u.x, acch1[4 * k + 0]);
            acch1[4 * k + 1] = fmaf(rd1, u.y, acch1[4 * k + 1]);
            acch1[4 * k + 2] = fmaf(rd1, u.z, acch1[4 * k + 2]);
            acch1[4 * k + 3] = fmaf(rd1, u.w, acch1[4 * k + 3]);
        }
    }
    // rhh dies; ht = tanh(acch) in place of acch
    float ht0[D_DIM], ht1[D_DIM];
    #pragma unroll
    for (int e = 0; e < D_DIM; ++e) {
        ht0[e] = fast_tanh(acch0[e]);
        ht1[e] = fast_tanh(acch1[e]);
    }

    // ---- Phase 3: accz = x*Wz + m*Vz + bz + hh @ Uz, fused with output ----
    float accz0[D_DIM], accz1[D_DIM];
    #pragma unroll
    for (int k = 0; k < 4; ++k) {
        float4 w = *reinterpret_cast<const float4*>(&sWz[4 * k]);
        float4 v = *reinterpret_cast<const float4*>(&sVz[4 * k]);
        float4 bi = *reinterpret_cast<const float4*>(&sbz[4 * k]);
        accz0[4 * k + 0] = fmaf(xb0, w.x, fmaf(mb0, v.x, bi.x));
        accz0[4 * k + 1] = fmaf(xb0, w.y, fmaf(mb0, v.y, bi.y));
        accz0[4 * k + 2] = fmaf(xb0, w.z, fmaf(mb0, v.z, bi.z));
        accz0[4 * k + 3] = fmaf(xb0, w.w, fmaf(mb0, v.w, bi.w));
        accz1[4 * k + 0] = fmaf(xb1, w.x, fmaf(mb1, v.x, bi.x));
        accz1[4 * k + 1] = fmaf(xb1, w.y, fmaf(mb1, v.y, bi.y));
        accz1[4 * k + 2] = fmaf(xb1, w.z, fmaf(mb1, v.z, bi.z));
        accz1[4 * k + 3] = fmaf(xb1, w.w, fmaf(mb1, v.w, bi.w));
    }
    #pragma unroll
    for (int d = 0; d < D_DIM; ++d) {
        const float hd0 = hh0[d];
        const float hd1 = hh1[d];
        #pragma unroll
        for (int k = 0; k < 4; ++k) {
            float4 u = *reinterpret_cast<const float4*>(&sUz[d * D_DIM + 4 * k]);
            accz0[4 * k + 0] = fmaf(hd0, u.x, accz0[4 * k + 0]);
            accz0[4 * k + 1] = fmaf(hd0, u.y, accz0[4 * k + 1]);
            accz0[4 * k + 2] = fmaf(hd0, u.z, accz0[4 * k + 2]);
            accz0[4 * k + 3] = fmaf(hd0, u.w, accz0[4 * k + 3]);
            accz1[4 * k + 0] = fmaf(hd1, u.x, accz1[4 * k + 0]);
            accz1[4 * k + 1] = fmaf(hd1, u.y, accz1[4 * k + 1]);
            accz1[4 * k + 2] = fmaf(hd1, u.z, accz1[4 * k + 2]);
            accz1[4 * k + 3] = fmaf(hd1, u.w, accz1[4 * k + 3]);
        }
    }

    // out = z * hh + (1 - z) * ht
    #pragma unroll
    for (int k = 0; k < 4; ++k) {
        float4 o;
        float zt = fast_sigmoid(accz0[4 * k + 0]);
        o.x = fmaf(zt, hh0[4 * k + 0] - ht0[4 * k + 0], ht0[4 * k + 0]);
        zt = fast_sigmoid(accz0[4 * k + 1]);
        o.y = fmaf(zt, hh0[4 * k + 1] - ht0[4 * k + 1], ht0[4 * k + 1]);
        zt = fast_sigmoid(accz0[4 * k + 2]);
        o.z = fmaf(zt, hh0[4 * k + 2] - ht0[4 * k + 2], ht0[4 * k + 2]);
        zt = fast_sigmoid(accz0[4 * k + 3]);
        o.w = fmaf(zt, hh0[4 * k + 3] - ht0[4 * k + 3], ht0[4 * k + 3]);
        *reinterpret_cast<float4*>(out + base0 + 4 * k) = o;
    }
    #pragma unroll
    for (int k = 0; k < 4; ++k) {
        float4 o;
        float zt = fast_sigmoid(accz1[4 * k + 0]);
        o.x = fmaf(zt, hh1[4 * k + 0] - ht1[4 * k + 0], ht1[4 * k + 0]);
        zt = fast_sigmoid(accz1[4 * k + 1]);
        o.y = fmaf(zt, hh1[4 * k + 1] - ht1[4 * k + 1], ht1[4 * k + 1]);
        zt = fast_sigmoid(accz1[4 * k + 2]);
        o.z = fmaf(zt, hh1[4 * k + 2] - ht1[4 * k + 2], ht1[4 * k + 2]);
        zt = fast_sigmoid(accz1[4 * k + 3]);
        o.w = fmaf(zt, hh1[4 * k + 3] - ht1[4 * k + 3], ht1[4 * k + 3]);
        *reinterpret_cast<float4*>(out + base1 + 4 * k) = o;
    }
}

extern "C" void kernel_launch(void* const* d_in, const int* in_sizes, int n_in,
                              void* d_out, int out_size, void* d_ws, size_t ws_size,
                              hipStream_t stream) {
    const float* h       = (const float*)d_in[0];
    const float* X       = (const float*)d_in[1];
    const float* M       = (const float*)d_in[2];
    const float* gamma_h = (const float*)d_in[3];
    const float* W_r     = (const float*)d_in[4];
    const float* W_z     = (const float*)d_in[5];
    const float* W_h     = (const float*)d_in[6];
    const float* U_r     = (const float*)d_in[7];
    const float* U_z     = (const float*)d_in[8];
    const float* U_h     = (const float*)d_in[9];
    const float* V_r     = (const float*)d_in[10];
    const float* V_z     = (const float*)d_in[11];
    const float* V_h     = (const float*)d_in[12];
    const float* b_r     = (const float*)d_in[13];
    const float* b_z     = (const float*)d_in[14];
    const float* b_h     = (const float*)d_in[15];
    float* out = (float*)d_out;

    const int B = 16384;
    dim3 grid(B / 512, I_TOT);   // (32, 128)
    dim3 block(256);
    gru_d_cell<<<grid, block, 0, stream>>>(h, X, M, gamma_h,
                                           W_r, W_z, W_h,
                                           U_r, U_z, U_h,
                                           V_r, V_z, V_h,
                                           b_r, b_z, b_h,
                                           out);
}

// Round 5
// 342.080 us; speedup vs baseline: 1.0668x; 1.0668x over previous
//
#include <hip/hip_runtime.h>
#include <hip/hip_bf16.h>

// GRU-D cell: B=16384, I=128, D=16.
// K=2 batch rows per thread so each LDS float4 broadcast of U feeds 8 FMAs,
// halving the per-CU LDS-pipe cost that bounded R3 (~123 us of ds_read_b128).
// R4's failure mode (compiler demoting per-thread float arrays to scratch,
// +580 MB of HBM spill traffic) is avoided by using ONLY named float4
// variables -- every access is a static struct member, nothing indexable.
// Peak live floats ~96 (+scalars) -> fits the 128-VGPR cap of
// __launch_bounds__(256,4).

constexpr int I_TOT = 128;
constexpr int D_DIM = 16;

__device__ __forceinline__ float4 f4fma(float s, float4 u, float4 a) {
    return make_float4(fmaf(s, u.x, a.x), fmaf(s, u.y, a.y),
                       fmaf(s, u.z, a.z), fmaf(s, u.w, a.w));
}

__device__ __forceinline__ float fast_sigmoid(float x) {
    float e = __expf(-x);
    return __builtin_amdgcn_rcpf(1.0f + e);
}

__device__ __forceinline__ float fast_tanh(float x) {
    x = fminf(fmaxf(x, -10.0f), 10.0f);
    float e = __expf(-2.0f * x);
    return (1.0f - e) * __builtin_amdgcn_rcpf(1.0f + e);
}

__device__ __forceinline__ float4 sig4(float4 x) {
    return make_float4(fast_sigmoid(x.x), fast_sigmoid(x.y),
                       fast_sigmoid(x.z), fast_sigmoid(x.w));
}

__device__ __forceinline__ float4 tanh4(float4 x) {
    return make_float4(fast_tanh(x.x), fast_tanh(x.y),
                       fast_tanh(x.z), fast_tanh(x.w));
}

__device__ __forceinline__ float4 mul4(float4 a, float4 b) {
    return make_float4(a.x * b.x, a.y * b.y, a.z * b.z, a.w * b.w);
}

// o = ht + z*(hh - ht)
__device__ __forceinline__ float4 blend4(float4 z, float4 hh, float4 ht) {
    return make_float4(fmaf(z.x, hh.x - ht.x, ht.x),
                       fmaf(z.y, hh.y - ht.y, ht.y),
                       fmaf(z.z, hh.z - ht.z, ht.z),
                       fmaf(z.w, hh.w - ht.w, ht.w));
}

#define LD4(arr, q) (*reinterpret_cast<const float4*>(&(arr)[4 * (q)]))

__global__ __launch_bounds__(256, 4) void gru_d_cell(
    const float* __restrict__ h,
    const float* __restrict__ X,
    const float* __restrict__ M,
    const float* __restrict__ gamma_h,
    const float* __restrict__ W_r,
    const float* __restrict__ W_z,
    const float* __restrict__ W_h,
    const float* __restrict__ U_r,
    const float* __restrict__ U_z,
    const float* __restrict__ U_h,
    const float* __restrict__ V_r,
    const float* __restrict__ V_z,
    const float* __restrict__ V_h,
    const float* __restrict__ b_r,
    const float* __restrict__ b_z,
    const float* __restrict__ b_h,
    float* __restrict__ out)
{
    __shared__ float sUr[256];
    __shared__ float sUz[256];
    __shared__ float sUh[256];
    __shared__ float sWr[16], sWz[16], sWh[16];
    __shared__ float sVr[16], sVz[16], sVh[16];
    __shared__ float sbr[16], sbz[16], sbh[16];

    const int i = blockIdx.y;        // block-uniform feature index
    const int t = threadIdx.x;

    sUr[t] = U_r[i * 256 + t];
    sUz[t] = U_z[i * 256 + t];
    sUh[t] = U_h[i * 256 + t];
    if (t < 16) {
        sWr[t] = W_r[i * 16 + t];
        sWz[t] = W_z[i * 16 + t];
        sWh[t] = W_h[i * 16 + t];
        sVr[t] = V_r[i * 16 + t];
        sVz[t] = V_z[i * 16 + t];
        sVh[t] = V_h[i * 16 + t];
        sbr[t] = b_r[i * 16 + t];
        sbz[t] = b_z[i * 16 + t];
        sbh[t] = b_h[i * 16 + t];
    }
    __syncthreads();

    const int b0 = blockIdx.x * 512 + t;
    const int b1 = b0 + 256;
    const size_t base0 = ((size_t)b0 * I_TOT + i) * D_DIM;
    const size_t base1 = ((size_t)b1 * I_TOT + i) * D_DIM;

    // hh = h * gamma_h (both rows), named float4s only
    float4 hh0a = mul4(*reinterpret_cast<const float4*>(h + base0 + 0),
                       *reinterpret_cast<const float4*>(gamma_h + base0 + 0));
    float4 hh0b = mul4(*reinterpret_cast<const float4*>(h + base0 + 4),
                       *reinterpret_cast<const float4*>(gamma_h + base0 + 4));
    float4 hh0c = mul4(*reinterpret_cast<const float4*>(h + base0 + 8),
                       *reinterpret_cast<const float4*>(gamma_h + base0 + 8));
    float4 hh0d = mul4(*reinterpret_cast<const float4*>(h + base0 + 12),
                       *reinterpret_cast<const float4*>(gamma_h + base0 + 12));
    float4 hh1a = mul4(*reinterpret_cast<const float4*>(h + base1 + 0),
                       *reinterpret_cast<const float4*>(gamma_h + base1 + 0));
    float4 hh1b = mul4(*reinterpret_cast<const float4*>(h + base1 + 4),
                       *reinterpret_cast<const float4*>(gamma_h + base1 + 4));
    float4 hh1c = mul4(*reinterpret_cast<const float4*>(h + base1 + 8),
                       *reinterpret_cast<const float4*>(gamma_h + base1 + 8));
    float4 hh1d = mul4(*reinterpret_cast<const float4*>(h + base1 + 12),
                       *reinterpret_cast<const float4*>(gamma_h + base1 + 12));

    const float xb0 = X[(size_t)b0 * I_TOT + i];
    const float mb0 = M[(size_t)b0 * I_TOT + i];
    const float xb1 = X[(size_t)b1 * I_TOT + i];
    const float mb1 = M[(size_t)b1 * I_TOT + i];

    float4 acc0a, acc0b, acc0c, acc0d, acc1a, acc1b, acc1c, acc1d;
    float4 tmp0a, tmp0b, tmp0c, tmp0d, tmp1a, tmp1b, tmp1c, tmp1d;

// acc init: x*W + m*V + b for both rows
#define ACC_INIT(sW, sV, sB)                                                  \
    {                                                                         \
        float4 w = LD4(sW, 0), v = LD4(sV, 0), bb = LD4(sB, 0);               \
        acc0a = f4fma(xb0, w, f4fma(mb0, v, bb));                             \
        acc1a = f4fma(xb1, w, f4fma(mb1, v, bb));                             \
        w = LD4(sW, 1); v = LD4(sV, 1); bb = LD4(sB, 1);                      \
        acc0b = f4fma(xb0, w, f4fma(mb0, v, bb));                             \
        acc1b = f4fma(xb1, w, f4fma(mb1, v, bb));                             \
        w = LD4(sW, 2); v = LD4(sV, 2); bb = LD4(sB, 2);                      \
        acc0c = f4fma(xb0, w, f4fma(mb0, v, bb));                             \
        acc1c = f4fma(xb1, w, f4fma(mb1, v, bb));                             \
        w = LD4(sW, 3); v = LD4(sV, 3); bb = LD4(sB, 3);                      \
        acc0d = f4fma(xb0, w, f4fma(mb0, v, bb));                             \
        acc1d = f4fma(xb1, w, f4fma(mb1, v, bb));                             \
    }

// one d-step: acc{0,1} += s{0,1} * U[d][:]
#define STEP(sU, d, s0, s1)                                                   \
    {                                                                         \
        float4 u0 = LD4(sU, 4 * (d) + 0);                                     \
        float4 u1 = LD4(sU, 4 * (d) + 1);                                     \
        float4 u2 = LD4(sU, 4 * (d) + 2);                                     \
        float4 u3 = LD4(sU, 4 * (d) + 3);                                     \
        acc0a = f4fma(s0, u0, acc0a); acc1a = f4fma(s1, u0, acc1a);           \
        acc0b = f4fma(s0, u1, acc0b); acc1b = f4fma(s1, u1, acc1b);           \
        acc0c = f4fma(s0, u2, acc0c); acc1c = f4fma(s1, u2, acc1c);           \
        acc0d = f4fma(s0, u3, acc0d); acc1d = f4fma(s1, u3, acc1d);           \
    }

#define MATVEC(sU, s0a, s0b, s0c, s0d, s1a, s1b, s1c, s1d)                    \
    STEP(sU, 0,  s0a.x, s1a.x) STEP(sU, 1,  s0a.y, s1a.y)                     \
    STEP(sU, 2,  s0a.z, s1a.z) STEP(sU, 3,  s0a.w, s1a.w)                     \
    STEP(sU, 4,  s0b.x, s1b.x) STEP(sU, 5,  s0b.y, s1b.y)                     \
    STEP(sU, 6,  s0b.z, s1b.z) STEP(sU, 7,  s0b.w, s1b.w)                     \
    STEP(sU, 8,  s0c.x, s1c.x) STEP(sU, 9,  s0c.y, s1c.y)                     \
    STEP(sU, 10, s0c.z, s1c.z) STEP(sU, 11, s0c.w, s1c.w)                     \
    STEP(sU, 12, s0d.x, s1d.x) STEP(sU, 13, s0d.y, s1d.y)                     \
    STEP(sU, 14, s0d.z, s1d.z) STEP(sU, 15, s0d.w, s1d.w)

    // ---- Phase 1: accr = x*Wr + m*Vr + br + hh @ Ur ----
    ACC_INIT(sWr, sVr, sbr)
    MATVEC(sUr, hh0a, hh0b, hh0c, hh0d, hh1a, hh1b, hh1c, hh1d)

    // tmp = rhh = sigmoid(accr) * hh   (acc dies, reused next phase)
    tmp0a = mul4(sig4(acc0a), hh0a); tmp0b = mul4(sig4(acc0b), hh0b);
    tmp0c = mul4(sig4(acc0c), hh0c); tmp0d = mul4(sig4(acc0d), hh0d);
    tmp1a = mul4(sig4(acc1a), hh1a); tmp1b = mul4(sig4(acc1b), hh1b);
    tmp1c = mul4(sig4(acc1c), hh1c); tmp1d = mul4(sig4(acc1d), hh1d);

    // ---- Phase 2: acch = x*Wh + m*Vh + bh + rhh @ Uh ----
    ACC_INIT(sWh, sVh, sbh)
    MATVEC(sUh, tmp0a, tmp0b, tmp0c, tmp0d, tmp1a, tmp1b, tmp1c, tmp1d)

    // tmp = ht = tanh(acch)   (rhh dies, ht takes its registers)
    tmp0a = tanh4(acc0a); tmp0b = tanh4(acc0b);
    tmp0c = tanh4(acc0c); tmp0d = tanh4(acc0d);
    tmp1a = tanh4(acc1a); tmp1b = tanh4(acc1b);
    tmp1c = tanh4(acc1c); tmp1d = tanh4(acc1d);

    // ---- Phase 3: accz = x*Wz + m*Vz + bz + hh @ Uz ----
    ACC_INIT(sWz, sVz, sbz)
    MATVEC(sUz, hh0a, hh0b, hh0c, hh0d, hh1a, hh1b, hh1c, hh1d)

    // out = ht + sigmoid(accz) * (hh - ht)
    {
        float4 o0 = blend4(sig4(acc0a), hh0a, tmp0a);
        float4 o1 = blend4(sig4(acc0b), hh0b, tmp0b);
        float4 o2 = blend4(sig4(acc0c), hh0c, tmp0c);
        float4 o3 = blend4(sig4(acc0d), hh0d, tmp0d);
        *reinterpret_cast<float4*>(out + base0 + 0)  = o0;
        *reinterpret_cast<float4*>(out + base0 + 4)  = o1;
        *reinterpret_cast<float4*>(out + base0 + 8)  = o2;
        *reinterpret_cast<float4*>(out + base0 + 12) = o3;
    }
    {
        float4 o0 = blend4(sig4(acc1a), hh1a, tmp1a);
        float4 o1 = blend4(sig4(acc1b), hh1b, tmp1b);
        float4 o2 = blend4(sig4(acc1c), hh1c, tmp1c);
        float4 o3 = blend4(sig4(acc1d), hh1d, tmp1d);
        *reinterpret_cast<float4*>(out + base1 + 0)  = o0;
        *reinterpret_cast<float4*>(out + base1 + 4)  = o1;
        *reinterpret_cast<float4*>(out + base1 + 8)  = o2;
        *reinterpret_cast<float4*>(out + base1 + 12) = o3;
    }
}

extern "C" void kernel_launch(void* const* d_in, const int* in_sizes, int n_in,
                              void* d_out, int out_size, void* d_ws, size_t ws_size,
                              hipStream_t stream) {
    const float* h       = (const float*)d_in[0];
    const float* X       = (const float*)d_in[1];
    const float* M       = (const float*)d_in[2];
    const float* gamma_h = (const float*)d_in[3];
    const float* W_r     = (const float*)d_in[4];
    const float* W_z     = (const float*)d_in[5];
    const float* W_h     = (const float*)d_in[6];
    const float* U_r     = (const float*)d_in[7];
    const float* U_z     = (const float*)d_in[8];
    const float* U_h     = (const float*)d_in[9];
    const float* V_r     = (const float*)d_in[10];
    const float* V_z     = (const float*)d_in[11];
    const float* V_h     = (const float*)d_in[12];
    const float* b_r     = (const float*)d_in[13];
    const float* b_z     = (const float*)d_in[14];
    const float* b_h     = (const float*)d_in[15];
    float* out = (float*)d_out;

    const int B = 16384;
    dim3 grid(B / 512, I_TOT);   // (32, 128)
    dim3 block(256);
    gru_d_cell<<<grid, block, 0, stream>>>(h, X, M, gamma_h,
                                           W_r, W_z, W_h,
                                           U_r, U_z, U_h,
                                           V_r, V_z, V_h,
                                           b_r, b_z, b_h,
                                           out);
}

// Round 6
// 136.088 us; speedup vs baseline: 2.6815x; 2.5137x over previous
//
#include <hip/hip_runtime.h>
#include <hip/hip_bf16.h>

// GRU-D cell: B=16384, I=128, D=16.
// K=2 batch rows per thread so each LDS float4 broadcast of U feeds 8 FMAs,
// halving the per-CU LDS-pipe cost that bounded R3 (~123 us of ds_read_b128).
//
// R4/R5 post-mortem: __launch_bounds__(256,4) acted as a 64-VGPR cap -> the
// allocator spilled ~50 floats/thread (~580 MB scratch HBM traffic). Fix:
// bare __launch_bounds__(256) + amdgpu_waves_per_eu(2,8) -> VGPR cap 256,
// compiler allocates the ~115 it needs (4 waves/SIMD), no spills.

constexpr int I_TOT = 128;
constexpr int D_DIM = 16;

__device__ __forceinline__ float4 f4fma(float s, float4 u, float4 a) {
    return make_float4(fmaf(s, u.x, a.x), fmaf(s, u.y, a.y),
                       fmaf(s, u.z, a.z), fmaf(s, u.w, a.w));
}

__device__ __forceinline__ float fast_sigmoid(float x) {
    float e = __expf(-x);
    return __builtin_amdgcn_rcpf(1.0f + e);
}

__device__ __forceinline__ float fast_tanh(float x) {
    x = fminf(fmaxf(x, -10.0f), 10.0f);
    float e = __expf(-2.0f * x);
    return (1.0f - e) * __builtin_amdgcn_rcpf(1.0f + e);
}

__device__ __forceinline__ float4 sig4(float4 x) {
    return make_float4(fast_sigmoid(x.x), fast_sigmoid(x.y),
                       fast_sigmoid(x.z), fast_sigmoid(x.w));
}

__device__ __forceinline__ float4 tanh4(float4 x) {
    return make_float4(fast_tanh(x.x), fast_tanh(x.y),
                       fast_tanh(x.z), fast_tanh(x.w));
}

__device__ __forceinline__ float4 mul4(float4 a, float4 b) {
    return make_float4(a.x * b.x, a.y * b.y, a.z * b.z, a.w * b.w);
}

// o = ht + z*(hh - ht)
__device__ __forceinline__ float4 blend4(float4 z, float4 hh, float4 ht) {
    return make_float4(fmaf(z.x, hh.x - ht.x, ht.x),
                       fmaf(z.y, hh.y - ht.y, ht.y),
                       fmaf(z.z, hh.z - ht.z, ht.z),
                       fmaf(z.w, hh.w - ht.w, ht.w));
}

#define LD4(arr, q) (*reinterpret_cast<const float4*>(&(arr)[4 * (q)]))

__global__ __launch_bounds__(256)
__attribute__((amdgpu_waves_per_eu(2, 8)))
void gru_d_cell(
    const float* __restrict__ h,
    const float* __restrict__ X,
    const float* __restrict__ M,
    const float* __restrict__ gamma_h,
    const float* __restrict__ W_r,
    const float* __restrict__ W_z,
    const float* __restrict__ W_h,
    const float* __restrict__ U_r,
    const float* __restrict__ U_z,
    const float* __restrict__ U_h,
    const float* __restrict__ V_r,
    const float* __restrict__ V_z,
    const float* __restrict__ V_h,
    const float* __restrict__ b_r,
    const float* __restrict__ b_z,
    const float* __restrict__ b_h,
    float* __restrict__ out)
{
    __shared__ float sUr[256];
    __shared__ float sUz[256];
    __shared__ float sUh[256];
    __shared__ float sWr[16], sWz[16], sWh[16];
    __shared__ float sVr[16], sVz[16], sVh[16];
    __shared__ float sbr[16], sbz[16], sbh[16];

    const int i = blockIdx.y;        // block-uniform feature index
    const int t = threadIdx.x;

    sUr[t] = U_r[i * 256 + t];
    sUz[t] = U_z[i * 256 + t];
    sUh[t] = U_h[i * 256 + t];
    if (t < 16) {
        sWr[t] = W_r[i * 16 + t];
        sWz[t] = W_z[i * 16 + t];
        sWh[t] = W_h[i * 16 + t];
        sVr[t] = V_r[i * 16 + t];
        sVz[t] = V_z[i * 16 + t];
        sVh[t] = V_h[i * 16 + t];
        sbr[t] = b_r[i * 16 + t];
        sbz[t] = b_z[i * 16 + t];
        sbh[t] = b_h[i * 16 + t];
    }
    __syncthreads();

    const int b0 = blockIdx.x * 512 + t;
    const int b1 = b0 + 256;
    const size_t base0 = ((size_t)b0 * I_TOT + i) * D_DIM;
    const size_t base1 = ((size_t)b1 * I_TOT + i) * D_DIM;

    // hh = h * gamma_h (both rows), named float4s only
    float4 hh0a = mul4(*reinterpret_cast<const float4*>(h + base0 + 0),
                       *reinterpret_cast<const float4*>(gamma_h + base0 + 0));
    float4 hh0b = mul4(*reinterpret_cast<const float4*>(h + base0 + 4),
                       *reinterpret_cast<const float4*>(gamma_h + base0 + 4));
    float4 hh0c = mul4(*reinterpret_cast<const float4*>(h + base0 + 8),
                       *reinterpret_cast<const float4*>(gamma_h + base0 + 8));
    float4 hh0d = mul4(*reinterpret_cast<const float4*>(h + base0 + 12),
                       *reinterpret_cast<const float4*>(gamma_h + base0 + 12));
    float4 hh1a = mul4(*reinterpret_cast<const float4*>(h + base1 + 0),
                       *reinterpret_cast<const float4*>(gamma_h + base1 + 0));
    float4 hh1b = mul4(*reinterpret_cast<const float4*>(h + base1 + 4),
                       *reinterpret_cast<const float4*>(gamma_h + base1 + 4));
    float4 hh1c = mul4(*reinterpret_cast<const float4*>(h + base1 + 8),
                       *reinterpret_cast<const float4*>(gamma_h + base1 + 8));
    float4 hh1d = mul4(*reinterpret_cast<const float4*>(h + base1 + 12),
                       *reinterpret_cast<const float4*>(gamma_h + base1 + 12));

    const float xb0 = X[(size_t)b0 * I_TOT + i];
    const float mb0 = M[(size_t)b0 * I_TOT + i];
    const float xb1 = X[(size_t)b1 * I_TOT + i];
    const float mb1 = M[(size_t)b1 * I_TOT + i];

    float4 acc0a, acc0b, acc0c, acc0d, acc1a, acc1b, acc1c, acc1d;
    float4 tmp0a, tmp0b, tmp0c, tmp0d, tmp1a, tmp1b, tmp1c, tmp1d;

// acc init: x*W + m*V + b for both rows
#define ACC_INIT(sW, sV, sB)                                                  \
    {                                                                         \
        float4 w = LD4(sW, 0), v = LD4(sV, 0), bb = LD4(sB, 0);               \
        acc0a = f4fma(xb0, w, f4fma(mb0, v, bb));                             \
        acc1a = f4fma(xb1, w, f4fma(mb1, v, bb));                             \
        w = LD4(sW, 1); v = LD4(sV, 1); bb = LD4(sB, 1);                      \
        acc0b = f4fma(xb0, w, f4fma(mb0, v, bb));                             \
        acc1b = f4fma(xb1, w, f4fma(mb1, v, bb));                             \
        w = LD4(sW, 2); v = LD4(sV, 2); bb = LD4(sB, 2);                      \
        acc0c = f4fma(xb0, w, f4fma(mb0, v, bb));                             \
        acc1c = f4fma(xb1, w, f4fma(mb1, v, bb));                             \
        w = LD4(sW, 3); v = LD4(sV, 3); bb = LD4(sB, 3);                      \
        acc0d = f4fma(xb0, w, f4fma(mb0, v, bb));                             \
        acc1d = f4fma(xb1, w, f4fma(mb1, v, bb));                             \
    }

// one d-step: acc{0,1} += s{0,1} * U[d][:]
#define STEP(sU, d, s0, s1)                                                   \
    {                                                                         \
        float4 u0 = LD4(sU, 4 * (d) + 0);                                     \
        float4 u1 = LD4(sU, 4 * (d) + 1);                                     \
        float4 u2 = LD4(sU, 4 * (d) + 2);                                     \
        float4 u3 = LD4(sU, 4 * (d) + 3);                                     \
        acc0a = f4fma(s0, u0, acc0a); acc1a = f4fma(s1, u0, acc1a);           \
        acc0b = f4fma(s0, u1, acc0b); acc1b = f4fma(s1, u1, acc1b);           \
        acc0c = f4fma(s0, u2, acc0c); acc1c = f4fma(s1, u2, acc1c);           \
        acc0d = f4fma(s0, u3, acc0d); acc1d = f4fma(s1, u3, acc1d);           \
    }

#define MATVEC(sU, s0a, s0b, s0c, s0d, s1a, s1b, s1c, s1d)                    \
    STEP(sU, 0,  s0a.x, s1a.x) STEP(sU, 1,  s0a.y, s1a.y)                     \
    STEP(sU, 2,  s0a.z, s1a.z) STEP(sU, 3,  s0a.w, s1a.w)                     \
    STEP(sU, 4,  s0b.x, s1b.x) STEP(sU, 5,  s0b.y, s1b.y)                     \
    STEP(sU, 6,  s0b.z, s1b.z) STEP(sU, 7,  s0b.w, s1b.w)                     \
    STEP(sU, 8,  s0c.x, s1c.x) STEP(sU, 9,  s0c.y, s1c.y)                     \
    STEP(sU, 10, s0c.z, s1c.z) STEP(sU, 11, s0c.w, s1c.w)                     \
    STEP(sU, 12, s0d.x, s1d.x) STEP(sU, 13, s0d.y, s1d.y)                     \
    STEP(sU, 14, s0d.z, s1d.z) STEP(sU, 15, s0d.w, s1d.w)

    // ---- Phase 1: accr = x*Wr + m*Vr + br + hh @ Ur ----
    ACC_INIT(sWr, sVr, sbr)
    MATVEC(sUr, hh0a, hh0b, hh0c, hh0d, hh1a, hh1b, hh1c, hh1d)

    // tmp = rhh = sigmoid(accr) * hh   (acc dies, reused next phase)
    tmp0a = mul4(sig4(acc0a), hh0a); tmp0b = mul4(sig4(acc0b), hh0b);
    tmp0c = mul4(sig4(acc0c), hh0c); tmp0d = mul4(sig4(acc0d), hh0d);
    tmp1a = mul4(sig4(acc1a), hh1a); tmp1b = mul4(sig4(acc1b), hh1b);
    tmp1c = mul4(sig4(acc1c), hh1c); tmp1d = mul4(sig4(acc1d), hh1d);

    // ---- Phase 2: acch = x*Wh + m*Vh + bh + rhh @ Uh ----
    ACC_INIT(sWh, sVh, sbh)
    MATVEC(sUh, tmp0a, tmp0b, tmp0c, tmp0d, tmp1a, tmp1b, tmp1c, tmp1d)

    // tmp = ht = tanh(acch)   (rhh dies, ht takes its registers)
    tmp0a = tanh4(acc0a); tmp0b = tanh4(acc0b);
    tmp0c = tanh4(acc0c); tmp0d = tanh4(acc0d);
    tmp1a = tanh4(acc1a); tmp1b = tanh4(acc1b);
    tmp1c = tanh4(acc1c); tmp1d = tanh4(acc1d);

    // ---- Phase 3: accz = x*Wz + m*Vz + bz + hh @ Uz ----
    ACC_INIT(sWz, sVz, sbz)
    MATVEC(sUz, hh0a, hh0b, hh0c, hh0d, hh1a, hh1b, hh1c, hh1d)

    // out = ht + sigmoid(accz) * (hh - ht)
    {
        float4 o0 = blend4(sig4(acc0a), hh0a, tmp0a);
        float4 o1 = blend4(sig4(acc0b), hh0b, tmp0b);
        float4 o2 = blend4(sig4(acc0c), hh0c, tmp0c);
        float4 o3 = blend4(sig4(acc0d), hh0d, tmp0d);
        *reinterpret_cast<float4*>(out + base0 + 0)  = o0;
        *reinterpret_cast<float4*>(out + base0 + 4)  = o1;
        *reinterpret_cast<float4*>(out + base0 + 8)  = o2;
        *reinterpret_cast<float4*>(out + base0 + 12) = o3;
    }
    {
        float4 o0 = blend4(sig4(acc1a), hh1a, tmp1a);
        float4 o1 = blend4(sig4(acc1b), hh1b, tmp1b);
        float4 o2 = blend4(sig4(acc1c), hh1c, tmp1c);
        float4 o3 = blend4(sig4(acc1d), hh1d, tmp1d);
        *reinterpret_cast<float4*>(out + base1 + 0)  = o0;
        *reinterpret_cast<float4*>(out + base1 + 4)  = o1;
        *reinterpret_cast<float4*>(out + base1 + 8)  = o2;
        *reinterpret_cast<float4*>(out + base1 + 12) = o3;
    }
}

extern "C" void kernel_launch(void* const* d_in, const int* in_sizes, int n_in,
                              void* d_out, int out_size, void* d_ws, size_t ws_size,
                              hipStream_t stream) {
    const float* h       = (const float*)d_in[0];
    const float* X       = (const float*)d_in[1];
    const float* M       = (const float*)d_in[2];
    const float* gamma_h = (const float*)d_in[3];
    const float* W_r     = (const float*)d_in[4];
    const float* W_z     = (const float*)d_in[5];
    const float* W_h     = (const float*)d_in[6];
    const float* U_r     = (const float*)d_in[7];
    const float* U_z     = (const float*)d_in[8];
    const float* U_h     = (const float*)d_in[9];
    const float* V_r     = (const float*)d_in[10];
    const float* V_z     = (const float*)d_in[11];
    const float* V_h     = (const float*)d_in[12];
    const float* b_r     = (const float*)d_in[13];
    const float* b_z     = (const float*)d_in[14];
    const float* b_h     = (const float*)d_in[15];
    float* out = (float*)d_out;

    const int B = 16384;
    dim3 grid(B / 512, I_TOT);   // (32, 128)
    dim3 block(256);
    gru_d_cell<<<grid, block, 0, stream>>>(h, X, M, gamma_h,
                                           W_r, W_z, W_h,
                                           U_r, U_z, U_h,
                                           V_r, V_z, V_h,
                                           b_r, b_z, b_h,
                                           out);
}